// Round 6
// baseline (729.585 us; speedup 1.0000x reference)
//
#include <hip/hip_runtime.h>
#include <hip/hip_fp16.h>

// Capsule dynamic routing, ONE fused kernel (plain launch), 3 grid syncs.
// x:[B,I,K]=32x2048x8, W:[J,I,D,K]=32x2048x16x8, out v:[B,J,D]=32x32x16.
// R12: R10/R11 showed per-barrier cost (~18us x5) is INVARIANT to barrier
// protocol (flag broadcast, staging changes: no effect). Remaining suspects:
// barrier COUNT and the writer-side __threadfence flushing dirty partials
// (buffer_wbl2 per barrier, ~1MB/XCD of fp16 partials, on the critical
// path). This version removes both causes:
//   - cross-block reduction via fp32 unsafeAtomicAdd into s_global[r]
//     (atomics execute at the coherence point: NO dirty L2 lines to flush),
//     8 replicas (bid&7) cap per-address contention at 32;
//   - every block reads the 8 replicas back (L2-deduped per XCD) and does
//     squash REDUNDANTLY in registers; running vsum lives in vreg[4][8],
//     never in memory -> reduce kernel/phase, partials, vsum all deleted;
//   - 1 sync per routing iteration = 3 total (was 5). Sync 3 is arrive-only
//     for blocks!=0; block 0 reduces sg[2] and writes out.
// Staging folded back in-kernel (R11 proved it off-critical-path).
// LDS padded to 87040B -> 1 block/CU forced, grid==256==#CUs co-resident.

#define ICAP    2048
#define JD      512          // JCAP*DDIM
#define S_ELEMS 16384        // BATCH*JCAP*DDIM
#define EPSQ    1e-7f
#define NBP     256          // blocks (one 8-i chunk each)
#define ICH     8            // i's per block
#define WROW    1040         // 64 slots x 16B + 16B pad
#define WIL     (8 * WROW)   // per-il LDS bytes
#define NRED    8            // s_global replicas (contention 256/NRED)

// gbar (unsigned words): [f*32] f=0..31 flag lines; [1024 + b*32] arrival
// slots (one 128B line per block).
#define GBAR_WORDS (1024 + NBP * 32)
#define SG_BYTES   ((size_t)3 * NRED * S_ELEMS * 4)   // 1.5 MB fp32

typedef _Float16 h2v __attribute__((ext_vector_type(2)));
union H8 { int4 i4; h2v h[4]; };

#if defined(__has_builtin) && __has_builtin(__builtin_amdgcn_fdot2)
#define FDOT2(a, b, c) __builtin_amdgcn_fdot2((a), (b), (c), false)
#else
__device__ inline float FDOT2(h2v a, h2v b, float c) {
    return c + (float)a[0] * (float)b[0] + (float)a[1] * (float)b[1];
}
#endif
#if defined(__has_builtin) && __has_builtin(__builtin_amdgcn_rcpf)
#define FAST_RCP(x) __builtin_amdgcn_rcpf(x)
#else
#define FAST_RCP(x) (1.0f / (x))
#endif
#if defined(__has_builtin) && __has_builtin(__builtin_amdgcn_rsqf)
#define FAST_RSQ(x) __builtin_amdgcn_rsqf(x)
#else
#define FAST_RSQ(x) rsqrtf(x)
#endif

// ---------------------------------------------------------------------------
// Grid barrier for generations 1,2 (full barrier: everyone waits).
// Distributed arrival slots + 32-way flag broadcast (proven R7-R11).
// Writer fence has nothing dirty to flush now (all data moved by atomics).
// ---------------------------------------------------------------------------
__device__ __forceinline__ void gsync12(unsigned* gb, unsigned gen,
                                        int bid, int tid) {
    __syncthreads();
    if (tid == 0) {
        __threadfence();     // release (cheap: no dirty lines)
        __hip_atomic_store(gb + 1024 + bid * 32, gen, __ATOMIC_RELAXED,
                           __HIP_MEMORY_SCOPE_AGENT);
    }
    if (bid == 0) {
        if (tid < 64) {
            const unsigned* s = gb + 1024 + tid * 32;
            for (;;) {
                bool done = true;
#pragma unroll
                for (int q = 0; q < 4; ++q) {
                    const unsigned v = __hip_atomic_load(
                        s + q * 2048, __ATOMIC_RELAXED,
                        __HIP_MEMORY_SCOPE_AGENT);
                    done &= (v >= gen);
                }
                if (__all(done)) break;
                __builtin_amdgcn_s_sleep(1);
            }
            __threadfence(); // acquire
            if (tid < 32)
                __hip_atomic_store(gb + tid * 32, gen, __ATOMIC_RELAXED,
                                   __HIP_MEMORY_SCOPE_AGENT);
        }
    } else if (tid == 0) {
        const unsigned* flag = gb + (bid & 31) * 32;
        while (__hip_atomic_load(flag, __ATOMIC_RELAXED,
                                 __HIP_MEMORY_SCOPE_AGENT) < gen)
            __builtin_amdgcn_s_sleep(16);
        __threadfence();     // acquire
    }
    __syncthreads();
}

// ---------------------------------------------------------------------------
// Fused kernel: 256 blocks x 512 threads (8 waves), 1 block/CU (LDS-forced).
// Wave w owns b in {w, w+8, w+16, w+24}; lane l -> j = l&31, dh = l>>5.
// Each thread covers e = b*512 + j*16 + dh*8 + q for q=0..7: the block's
// threads jointly cover ALL 16384 outputs -> squash is done locally by
// every block (no second barrier per iteration).
// ---------------------------------------------------------------------------
__global__ __launch_bounds__(512, 1)
void caps_fused(const float4* __restrict__ Wv, const float4* __restrict__ Xv,
                float* __restrict__ sg, float* __restrict__ out,
                unsigned* __restrict__ gbar)
{
    // 82944 + 4096 = 87040 B total: 2 blocks cannot co-reside (>160KB).
    __shared__ __align__(16) unsigned char sWt[82944];   // 66560 used, rest pad
    __shared__ __align__(16) unsigned char sX[4096];     // 32b x 8il x 16B

    const int tid = threadIdx.x;
    const int bid = blockIdx.x;
    const int i0  = bid * ICH;

    // ---- stage W: fp32 global -> f16 LDS in pass layout (R9-proven) ----
    // slot (il, d&7 row, s=2j+dh) holds W[j, i0+il, d, k=0..7] as 8 halves.
#pragma unroll
    for (int it = 0; it < 16; ++it) {
        const int f  = it * 512 + tid;          // [0, 8192) float4s
        const int q4 = f & 31;
        const int il = (f >> 5) & 7;
        const int jj = f >> 8;
        const float4 w = Wv[((size_t)jj * ICAP + (i0 + il)) * 32 + q4];
        ushort4 h;
        h.x = __half_as_ushort(__float2half(w.x));
        h.y = __half_as_ushort(__float2half(w.y));
        h.z = __half_as_ushort(__float2half(w.z));
        h.w = __half_as_ushort(__float2half(w.w));
        const int d   = q4 >> 1;
        const int sub = q4 & 1;
        *reinterpret_cast<ushort4*>(sWt + il * WIL + (d & 7) * WROW
                                    + (2 * jj + (d >> 3)) * 16 + sub * 8) = h;
    }
    // ---- stage x: fp32 global -> f16 LDS ----
    {
        const int k4 = tid & 1, il = (tid >> 1) & 7, b = tid >> 4;
        const float4 w = Xv[((size_t)b * ICAP + (i0 + il)) * 2 + k4];
        ushort4 h;
        h.x = __half_as_ushort(__float2half(w.x));
        h.y = __half_as_ushort(__float2half(w.y));
        h.z = __half_as_ushort(__float2half(w.z));
        h.w = __half_as_ushort(__float2half(w.w));
        *reinterpret_cast<ushort4*>(sX + (b * 8 + il) * 16 + k4 * 8) = h;
    }
    __syncthreads();

    const int wave = tid >> 6, lane = tid & 63;
    const int j = lane & 31, dh = lane >> 5;

    float vreg[4][8];                            // running vsum, in registers
#pragma unroll
    for (int bb = 0; bb < 4; ++bb)
#pragma unroll
        for (int q = 0; q < 8; ++q) vreg[bb][q] = 0.f;

#pragma unroll
    for (int r = 0; r < 3; ++r) {
        const bool first = (r == 0);             // constant after unroll
        float sacc[4][8];
#pragma unroll
        for (int bb = 0; bb < 4; ++bb)
#pragma unroll
            for (int q = 0; q < 8; ++q) sacc[bb][q] = 0.f;

#pragma unroll
        for (int il = 0; il < ICH; ++il) {
            H8 w8[8];
#pragma unroll
            for (int cc = 0; cc < 8; ++cc)
                w8[cc].i4 = *reinterpret_cast<const int4*>(
                    sWt + il * WIL + cc * WROW + (2 * j + dh) * 16);
#pragma unroll
            for (int bb = 0; bb < 4; ++bb) {
                const int b = wave + 8 * bb;
                H8 xv;
                xv.i4 = *reinterpret_cast<const int4*>(sX + (b * 8 + il) * 16);

                float u[8], tpart = 0.f;
#pragma unroll
                for (int q = 0; q < 8; ++q) {
                    float acc = FDOT2(w8[q].h[0], xv.h[0], 0.f);
                    acc = FDOT2(w8[q].h[1], xv.h[1], acc);
                    acc = FDOT2(w8[q].h[2], xv.h[2], acc);
                    acc = FDOT2(w8[q].h[3], xv.h[3], acc);
                    u[q] = acc;
                    if (!first) tpart = fmaf(acc, vreg[bb][q], tpart);
                }
                float c;
                if (first) {
                    c = 0.03125f;                // softmax(0) over 32 j's
                } else {
                    const float t = tpart + __shfl_xor(tpart, 32);
                    const float e = __expf(t);
                    float se = e;
#pragma unroll
                    for (int off = 1; off <= 16; off <<= 1)
                        se += __shfl_xor(se, off);
                    c = e * FAST_RCP(se);
                }
#pragma unroll
                for (int q = 0; q < 8; ++q)
                    sacc[bb][q] = fmaf(c, u[q], sacc[bb][q]);
            }
        }

        // ---- cross-block reduce: fp32 atomics into replica bid&(NRED-1) ----
        {
            float* sgr = sg + (size_t)(r * NRED + (bid & (NRED - 1))) * S_ELEMS;
#pragma unroll
            for (int bb = 0; bb < 4; ++bb) {
                float* p = sgr + (wave + 8 * bb) * JD + j * 16 + dh * 8;
#pragma unroll
                for (int q = 0; q < 8; ++q)
                    unsafeAtomicAdd(p + q, sacc[bb][q]);
            }
        }

        if (r < 2) {
            gsync12(gbar, r + 1, bid, tid);
            // ---- local squash: sum replicas, v = squash(s), vreg += v ----
            const float* sb = sg + (size_t)r * NRED * S_ELEMS;
#pragma unroll
            for (int bb = 0; bb < 4; ++bb) {
                const int e0 = (wave + 8 * bb) * JD + j * 16 + dh * 8;
                float sv[8] = {0.f,0.f,0.f,0.f,0.f,0.f,0.f,0.f};
#pragma unroll
                for (int rep = 0; rep < NRED; ++rep) {
                    const float4* p = reinterpret_cast<const float4*>(
                        sb + (size_t)rep * S_ELEMS + e0);
                    const float4 a = p[0], c = p[1];
                    sv[0] += a.x; sv[1] += a.y; sv[2] += a.z; sv[3] += a.w;
                    sv[4] += c.x; sv[5] += c.y; sv[6] += c.z; sv[7] += c.w;
                }
                float n2 = 0.f;
#pragma unroll
                for (int q = 0; q < 8; ++q) n2 = fmaf(sv[q], sv[q], n2);
                n2 += __shfl_xor(n2, 32);        // both d-halves
                const float scale = n2 * FAST_RCP(1.f + n2) * FAST_RSQ(n2 + EPSQ);
#pragma unroll
                for (int q = 0; q < 8; ++q)
                    vreg[bb][q] = fmaf(sv[q], scale, vreg[bb][q]);
            }
        } else {
            // ---- final sync: others arrive & exit; block 0 writes out ----
            __syncthreads();
            if (tid == 0) {
                __threadfence();
                __hip_atomic_store(gbar + 1024 + bid * 32, 3u,
                                   __ATOMIC_RELAXED, __HIP_MEMORY_SCOPE_AGENT);
            }
            if (bid != 0) return;
            if (tid < 64) {
                const unsigned* s = gbar + 1024 + tid * 32;
                for (;;) {
                    bool done = true;
#pragma unroll
                    for (int qq = 0; qq < 4; ++qq) {
                        const unsigned v = __hip_atomic_load(
                            s + qq * 2048, __ATOMIC_RELAXED,
                            __HIP_MEMORY_SCOPE_AGENT);
                        done &= (v >= 3u);
                    }
                    if (__all(done)) break;
                    __builtin_amdgcn_s_sleep(1);
                }
            }
            __threadfence();                     // acquire
            __syncthreads();
            const float* sb = sg + (size_t)2 * NRED * S_ELEMS;
#pragma unroll
            for (int bb = 0; bb < 4; ++bb) {
                const int e0 = (wave + 8 * bb) * JD + j * 16 + dh * 8;
                float sv[8] = {0.f,0.f,0.f,0.f,0.f,0.f,0.f,0.f};
#pragma unroll
                for (int rep = 0; rep < NRED; ++rep) {
                    const float4* p = reinterpret_cast<const float4*>(
                        sb + (size_t)rep * S_ELEMS + e0);
                    const float4 a = p[0], c = p[1];
                    sv[0] += a.x; sv[1] += a.y; sv[2] += a.z; sv[3] += a.w;
                    sv[4] += c.x; sv[5] += c.y; sv[6] += c.z; sv[7] += c.w;
                }
                float n2 = 0.f;
#pragma unroll
                for (int q = 0; q < 8; ++q) n2 = fmaf(sv[q], sv[q], n2);
                n2 += __shfl_xor(n2, 32);
                const float scale = n2 * FAST_RCP(1.f + n2) * FAST_RSQ(n2 + EPSQ);
                float4 o0, o1;
                o0.x = sv[0] * scale; o0.y = sv[1] * scale;
                o0.z = sv[2] * scale; o0.w = sv[3] * scale;
                o1.x = sv[4] * scale; o1.y = sv[5] * scale;
                o1.z = sv[6] * scale; o1.w = sv[7] * scale;
                float4* op = reinterpret_cast<float4*>(out + e0);
                op[0] = o0; op[1] = o1;
            }
        }
    }
}

extern "C" void kernel_launch(void* const* d_in, const int* in_sizes, int n_in,
                              void* d_out, int out_size, void* d_ws, size_t ws_size,
                              hipStream_t stream) {
    const float* x = (const float*)d_in[0];   // [32,2048,8]
    const float* W = (const float*)d_in[1];   // [32,2048,16,8]
    float* out = (float*)d_out;               // [32,32,16]

    // ws: gbar 36KB | s_global 1.5MB (3 passes x 8 replicas x 64KB)
    unsigned* gbar = (unsigned*)d_ws;
    float*    sg   = (float*)((char*)d_ws + GBAR_WORDS * sizeof(unsigned));

    // zero barrier state + atomic accumulators (every replay)
    hipMemsetAsync(d_ws, 0, GBAR_WORDS * sizeof(unsigned) + SG_BYTES, stream);

    caps_fused<<<NBP, 512, 0, stream>>>((const float4*)W, (const float4*)x,
                                        sg, out, gbar);
}

// Round 8
// 411.649 us; speedup vs baseline: 1.7723x; 1.7723x over previous
//
#include <hip/hip_runtime.h>
#include <hip/hip_fp16.h>

// Capsule dynamic routing, ONE fused kernel (plain launch), 5 grid syncs.
// x:[B,I,K]=32x2048x8, W:[J,I,D,K]=32x2048x16x8, out v:[B,J,D]=32x32x16.
// R13: R12's fp32-atomic reduction refuted (WRITE 607MB: every atomic
// dirties a line at the coherence point). Back to R9's proven structure
// (kernel 113us) with two changes aimed at the protocol-INVARIANT ~18us/sync
// cost (R10/R11 null results -> it's the full-grid drain/straggler tail,
// not the protocol):
//   1) grid 256 -> 128 blocks (ICH 16): half the barrier participants,
//      double work per block -> relative completion spread shrinks.
//      LDS 143KB still forces 1 block/CU.
//   2) partials written with NONTEMPORAL stores (+NT loads in reduce):
//      no dirty L2 partials -> writer-side release fence (buffer_wbl2)
//      has no MB-scale payload on the barrier critical path.
// Distributed arrival slots + 32-line flag broadcast kept (R10-proven).
// (R13b: NT store operand must be a clang ext_vector type, not HIP int4.)

#define ICAP    2048
#define JD      512          // JCAP*DDIM
#define S_ELEMS 16384        // BATCH*JCAP*DDIM
#define EPSQ    1e-7f
#define NBP     128          // blocks (one 16-i chunk each)
#define ICH     16           // i's per block
#define WROW    1040         // 64 slots x 16B + 16B pad
#define WIL     (8 * WROW)   // per-il LDS bytes (8 d-rows)

// gbar (unsigned words): [f*32] f=0..31 flag lines; [1024 + b*32] arrival
// slots (one 128B line per block).
#define GBAR_WORDS (1024 + NBP * 32)

typedef _Float16 h2v __attribute__((ext_vector_type(2)));
typedef int      i4v __attribute__((ext_vector_type(4)));
union H8 { int4 i4; h2v h[4]; };

#if defined(__has_builtin) && __has_builtin(__builtin_amdgcn_fdot2)
#define FDOT2(a, b, c) __builtin_amdgcn_fdot2((a), (b), (c), false)
#else
__device__ inline float FDOT2(h2v a, h2v b, float c) {
    return c + (float)a[0] * (float)b[0] + (float)a[1] * (float)b[1];
}
#endif
#if defined(__has_builtin) && __has_builtin(__builtin_amdgcn_rcpf)
#define FAST_RCP(x) __builtin_amdgcn_rcpf(x)
#else
#define FAST_RCP(x) (1.0f / (x))
#endif
#if defined(__has_builtin) && __has_builtin(__builtin_amdgcn_rsqf)
#define FAST_RSQ(x) __builtin_amdgcn_rsqf(x)
#else
#define FAST_RSQ(x) rsqrtf(x)
#endif

// ---------------------------------------------------------------------------
// Distributed-arrival grid barrier, 128 participants, 32-way flag broadcast.
// Requires co-resident grid (LDS capacity forces 1 block/CU, grid < #CUs)
// and zeroed state. Generations 1-based, monotone within a launch.
// ---------------------------------------------------------------------------
__device__ __forceinline__ void gsync(unsigned* gb, unsigned gen,
                                      int bid, int tid) {
    __syncthreads();
    if (tid == 0) {
        __threadfence();     // release (cheap: partials are NT, little dirty)
        __hip_atomic_store(gb + 1024 + bid * 32, gen, __ATOMIC_RELAXED,
                           __HIP_MEMORY_SCOPE_AGENT);
    }
    if (bid == 0) {
        if (tid < 64) {
            const unsigned* s = gb + 1024 + tid * 32;
            for (;;) {
                bool done = true;
#pragma unroll
                for (int q = 0; q < 2; ++q) {      // 128 slots = 64 lanes x 2
                    const unsigned v = __hip_atomic_load(
                        s + q * 2048, __ATOMIC_RELAXED,
                        __HIP_MEMORY_SCOPE_AGENT);
                    done &= (v >= gen);
                }
                if (__all(done)) break;
                __builtin_amdgcn_s_sleep(1);
            }
            __threadfence(); // acquire (transitive to flag stores)
            if (tid < 32)
                __hip_atomic_store(gb + tid * 32, gen, __ATOMIC_RELAXED,
                                   __HIP_MEMORY_SCOPE_AGENT);
        }
    } else if (tid == 0) {
        const unsigned* flag = gb + (bid & 31) * 32;
        while (__hip_atomic_load(flag, __ATOMIC_RELAXED,
                                 __HIP_MEMORY_SCOPE_AGENT) < gen)
            __builtin_amdgcn_s_sleep(8);
        __threadfence();     // acquire
    }
    __syncthreads();
}

// ---------------------------------------------------------------------------
// Fused kernel: 128 blocks x 512 threads (8 waves), 1 block/CU (LDS-forced).
// Wave w owns b in {w, w+8, w+16, w+24}; lane l -> j = l&31, dh = l>>5.
// LDS: sWt 130KB (f16 W chunk, pass layout), sX 8KB, rbuf 2KB = 143KB.
// ---------------------------------------------------------------------------
__global__ __launch_bounds__(512, 1)
void caps_fused(const float4* __restrict__ Wv, const float4* __restrict__ Xv,
                float* __restrict__ vsum, __half* __restrict__ partials,
                float* __restrict__ out, unsigned* __restrict__ gbar)
{
    __shared__ __align__(16) unsigned char sWt[WIL * ICH];   // 133120 B
    __shared__ __align__(16) unsigned char sX[8192];         // 32b x 16il x 16B
    __shared__ float rbuf[4][128];

    const int tid = threadIdx.x;
    const int bid = blockIdx.x;
    const int i0  = bid * ICH;

    // ---- stage W: fp32 global -> f16 LDS in pass layout ----
    // slot (il, d&7 row, s=2j+dh) holds W[j, i0+il, d, k=0..7] as 8 halves.
#pragma unroll 4
    for (int it = 0; it < 32; ++it) {
        const int f  = it * 512 + tid;          // [0, 16384) float4s
        const int q4 = f & 31;
        const int il = (f >> 5) & 15;
        const int jj = f >> 9;
        const float4 w = Wv[((size_t)jj * ICAP + (i0 + il)) * 32 + q4];
        ushort4 h;
        h.x = __half_as_ushort(__float2half(w.x));
        h.y = __half_as_ushort(__float2half(w.y));
        h.z = __half_as_ushort(__float2half(w.z));
        h.w = __half_as_ushort(__float2half(w.w));
        const int d   = q4 >> 1;
        const int sub = q4 & 1;
        *reinterpret_cast<ushort4*>(sWt + il * WIL + (d & 7) * WROW
                                    + (2 * jj + (d >> 3)) * 16 + sub * 8) = h;
    }
    // ---- stage x: fp32 global -> f16 LDS, slot (b*16+il)*16B = x[b,i,0..7] --
#pragma unroll
    for (int it = 0; it < 2; ++it) {
        const int f  = it * 512 + tid;          // [0, 1024) float4s
        const int k4 = f & 1, il = (f >> 1) & 15, b = f >> 5;
        const float4 w = Xv[((size_t)b * ICAP + (i0 + il)) * 2 + k4];
        ushort4 h;
        h.x = __half_as_ushort(__float2half(w.x));
        h.y = __half_as_ushort(__float2half(w.y));
        h.z = __half_as_ushort(__float2half(w.z));
        h.w = __half_as_ushort(__float2half(w.w));
        *reinterpret_cast<ushort4*>(sX + (b * 16 + il) * 16 + k4 * 8) = h;
    }
    __syncthreads();

    const int wave = tid >> 6, lane = tid & 63;
    const int j = lane & 31, dh = lane >> 5;
    float vacc = 0.f;                            // tid<128: running vsum[e]

#pragma unroll
    for (int r = 0; r < 3; ++r) {
        const bool first = (r == 0);             // constant after unroll
        float vs[4][8], sacc[4][8];
#pragma unroll
        for (int bb = 0; bb < 4; ++bb) {
            const int b = wave + 8 * bb;
            if (!first) {
                const float* vp = vsum + b * JD + j * 16 + dh * 8;
                const float4 a  = *reinterpret_cast<const float4*>(vp);
                const float4 bq = *reinterpret_cast<const float4*>(vp + 4);
                vs[bb][0]=a.x; vs[bb][1]=a.y; vs[bb][2]=a.z; vs[bb][3]=a.w;
                vs[bb][4]=bq.x; vs[bb][5]=bq.y; vs[bb][6]=bq.z; vs[bb][7]=bq.w;
            }
#pragma unroll
            for (int q = 0; q < 8; ++q) sacc[bb][q] = 0.f;
        }

#pragma unroll
        for (int il = 0; il < ICH; ++il) {
            H8 w8[8];
#pragma unroll
            for (int cc = 0; cc < 8; ++cc)
                w8[cc].i4 = *reinterpret_cast<const int4*>(
                    sWt + il * WIL + cc * WROW + (2 * j + dh) * 16);
#pragma unroll
            for (int bb = 0; bb < 4; ++bb) {
                const int b = wave + 8 * bb;
                H8 xv;
                xv.i4 = *reinterpret_cast<const int4*>(sX + (b * 16 + il) * 16);

                float u[8], tpart = 0.f;
#pragma unroll
                for (int q = 0; q < 8; ++q) {
                    float acc = FDOT2(w8[q].h[0], xv.h[0], 0.f);
                    acc = FDOT2(w8[q].h[1], xv.h[1], acc);
                    acc = FDOT2(w8[q].h[2], xv.h[2], acc);
                    acc = FDOT2(w8[q].h[3], xv.h[3], acc);
                    u[q] = acc;
                    if (!first) tpart = fmaf(acc, vs[bb][q], tpart);
                }
                float c;
                if (first) {
                    c = 0.03125f;                // softmax(0) over 32 j's
                } else {
                    const float t = tpart + __shfl_xor(tpart, 32);
                    const float e = __expf(t);
                    float se = e;
#pragma unroll
                    for (int off = 1; off <= 16; off <<= 1)
                        se += __shfl_xor(se, off);
                    c = e * FAST_RCP(se);
                }
#pragma unroll
                for (int q = 0; q < 8; ++q)
                    sacc[bb][q] = fmaf(c, u[q], sacc[bb][q]);
            }
        }

        // fp16 partial slice, disjoint per block, NONTEMPORAL (no L2 alloc)
        __half* pout = partials + (size_t)bid * S_ELEMS;
#pragma unroll
        for (int bb = 0; bb < 4; ++bb) {
            const int b = wave + 8 * bb;
            union { i4v v; __half2 h[4]; } pk;
#pragma unroll
            for (int q = 0; q < 4; ++q)
                pk.h[q] = __floats2half2_rn(sacc[bb][2 * q], sacc[bb][2 * q + 1]);
            __builtin_nontemporal_store(
                pk.v, reinterpret_cast<i4v*>(pout + b * JD + j * 16 + dh * 8));
        }

        gsync(gbar, 2 * r + 1, bid, tid);

        // ---- reduce: block owns e in [bid*128, bid*128+128) ----
        {
            const int eL = tid & 127;
            const int sg = tid >> 7;             // 4 groups x 32 slices
            const int e  = bid * 128 + eL;
            float s = 0.f;
            const ushort* p = reinterpret_cast<const ushort*>(partials)
                              + (size_t)sg * 32 * S_ELEMS + e;
#pragma unroll
            for (int n = 0; n < 32; ++n)
                s += __half2float(__ushort_as_half(
                    __builtin_nontemporal_load(p + (size_t)n * S_ELEMS)));
            rbuf[sg][eL] = s;
            __syncthreads();
            if (tid < 128) {
                s = rbuf[0][eL] + rbuf[1][eL] + rbuf[2][eL] + rbuf[3][eL];
                float n2 = s * s;
#pragma unroll
                for (int off = 1; off <= 8; off <<= 1)
                    n2 += __shfl_xor(n2, off);   // sum over d=16 (e-contiguous)
                const float scale = n2 * FAST_RCP(1.f + n2) * FAST_RSQ(n2 + EPSQ);
                const float v = s * scale;
                if (r == 2) {
                    out[e] = v;
                } else {
                    vacc += v;                   // vsum = sum of v's so far
                    vsum[e] = vacc;
                }
            }
        }
        if (r < 2) gsync(gbar, 2 * r + 2, bid, tid);
    }
}

extern "C" void kernel_launch(void* const* d_in, const int* in_sizes, int n_in,
                              void* d_out, int out_size, void* d_ws, size_t ws_size,
                              hipStream_t stream) {
    const float* x = (const float*)d_in[0];   // [32,2048,8]
    const float* W = (const float*)d_in[1];   // [32,2048,16,8]
    float* out = (float*)d_out;               // [32,32,16]

    // ws: vsum 64KB | partials fp16 4.19MB (128 slices) | gbar 20KB
    float*    vsum     = (float*)d_ws;
    __half*   partials = (__half*)((char*)d_ws + 65536);
    unsigned* gbar     = (unsigned*)((char*)partials + (size_t)NBP * S_ELEMS * 2);

    // zero barrier state (32 flag lines + 128 arrival slots)
    (void)hipMemsetAsync(gbar, 0, GBAR_WORDS * sizeof(unsigned), stream);

    caps_fused<<<NBP, 512, 0, stream>>>((const float4*)W, (const float4*)x,
                                        vsum, partials, out, gbar);
}